// Round 1
// baseline (190.290 us; speedup 1.0000x reference)
//
#include <hip/hip_runtime.h>

// Problem: B=32, C=1, H=512, W=512 fp32. Haar DWT is linear, so
// (i_X - t_X) = DWT_X(input - target); fuse everything into one pass.
// loss_low  = mean |0.5(da+db+dc+dd)|                over B*(H/2)*(W/2)
// loss_high = mean(|lh|+|hl|+|hh|) / 3

#define HH 512
#define WW 512
// N_LOW = 32 * 256 * 256
static constexpr float N_LOW = 2097152.0f;

__global__ __launch_bounds__(256) void haar_loss_kernel(
    const float* __restrict__ inp, const float* __restrict__ tgt,
    float* __restrict__ ws)
{
    const int idx = blockIdx.x * 256 + threadIdx.x;
    // idx in [0, 1048576): b*(256*128) + r*128 + c4
    const int c4 = idx & 127;          // which group of 4 columns
    const int r  = (idx >> 7) & 255;   // row-pair index
    const int b  = idx >> 15;          // batch
    const int base0 = b * (HH * WW) + (2 * r) * WW + 4 * c4;

    const float4 i0 = *(const float4*)(inp + base0);
    const float4 i1 = *(const float4*)(inp + base0 + WW);
    const float4 t0 = *(const float4*)(tgt + base0);
    const float4 t1 = *(const float4*)(tgt + base0 + WW);

    float sl = 0.f, sh = 0.f;
    {
        const float da = i0.x - t0.x, db = i0.y - t0.y;
        const float dc = i1.x - t1.x, dd = i1.y - t1.y;
        sl += fabsf(0.5f * ( da + db + dc + dd));
        sh += fabsf(0.5f * (-da - db + dc + dd))
            + fabsf(0.5f * (-da + db - dc + dd))
            + fabsf(0.5f * ( da - db - dc + dd));
    }
    {
        const float da = i0.z - t0.z, db = i0.w - t0.w;
        const float dc = i1.z - t1.z, dd = i1.w - t1.w;
        sl += fabsf(0.5f * ( da + db + dc + dd));
        sh += fabsf(0.5f * (-da - db + dc + dd))
            + fabsf(0.5f * (-da + db - dc + dd))
            + fabsf(0.5f * ( da - db - dc + dd));
    }

    // wave-64 butterfly reduce
    #pragma unroll
    for (int off = 32; off > 0; off >>= 1) {
        sl += __shfl_down(sl, off, 64);
        sh += __shfl_down(sh, off, 64);
    }

    __shared__ float red[8];  // 4 waves x {low, high}
    const int lane = threadIdx.x & 63;
    const int wave = threadIdx.x >> 6;
    if (lane == 0) { red[wave] = sl; red[4 + wave] = sh; }
    __syncthreads();
    if (threadIdx.x == 0) {
        const float tl = red[0] + red[1] + red[2] + red[3];
        const float th = red[4] + red[5] + red[6] + red[7];
        atomicAdd(&ws[0], tl);   // device-scope by default (G12)
        atomicAdd(&ws[1], th);
    }
}

__global__ void haar_finalize_kernel(const float* __restrict__ ws,
                                     float* __restrict__ out)
{
    if (threadIdx.x == 0) {
        out[0] = ws[0] / N_LOW;
        out[1] = ws[1] / (3.0f * N_LOW);
    }
}

extern "C" void kernel_launch(void* const* d_in, const int* in_sizes, int n_in,
                              void* d_out, int out_size, void* d_ws, size_t ws_size,
                              hipStream_t stream) {
    const float* inp = (const float*)d_in[0];
    const float* tgt = (const float*)d_in[1];
    float* out = (float*)d_out;
    float* ws  = (float*)d_ws;

    // ws is re-poisoned to 0xAA before every timed launch — zero it on-stream.
    hipMemsetAsync(ws, 0, 2 * sizeof(float), stream);

    // 1,048,576 work items (one per 4-col x 2-row patch) / 256 = 4096 blocks
    haar_loss_kernel<<<4096, 256, 0, stream>>>(inp, tgt, ws);
    haar_finalize_kernel<<<1, 64, 0, stream>>>(ws, out);
}

// Round 2
// 95.208 us; speedup vs baseline: 1.9987x; 1.9987x over previous
//
#include <hip/hip_runtime.h>

// B=32, C=1, H=512, W=512 fp32. Haar DWT is linear:
// (i_X - t_X) = DWT_X(input - target) -> single fused pass.
// R1 change: same-address atomicAdd (8192 serialized device-scope atomics,
// ~100us of drain) replaced by per-block plain stores + tree reduce in the
// finalize kernel. 2 graph nodes, no memset needed (ws fully overwritten).

#define HH 512
#define WW 512
#define NBLK 4096
static constexpr float N_LOW = 2097152.0f;  // 32 * 256 * 256

__global__ __launch_bounds__(256) void haar_loss_kernel(
    const float* __restrict__ inp, const float* __restrict__ tgt,
    float* __restrict__ ws)
{
    const int idx = blockIdx.x * 256 + threadIdx.x;
    // idx in [0, 1048576): b*(256*128) + r*128 + c4
    const int c4 = idx & 127;          // group of 4 columns
    const int r  = (idx >> 7) & 255;   // row-pair index
    const int b  = idx >> 15;          // batch
    const int base0 = b * (HH * WW) + (2 * r) * WW + 4 * c4;

    const float4 i0 = *(const float4*)(inp + base0);
    const float4 i1 = *(const float4*)(inp + base0 + WW);
    const float4 t0 = *(const float4*)(tgt + base0);
    const float4 t1 = *(const float4*)(tgt + base0 + WW);

    float sl = 0.f, sh = 0.f;
    {
        const float da = i0.x - t0.x, db = i0.y - t0.y;
        const float dc = i1.x - t1.x, dd = i1.y - t1.y;
        sl += fabsf(0.5f * ( da + db + dc + dd));
        sh += fabsf(0.5f * (-da - db + dc + dd))
            + fabsf(0.5f * (-da + db - dc + dd))
            + fabsf(0.5f * ( da - db - dc + dd));
    }
    {
        const float da = i0.z - t0.z, db = i0.w - t0.w;
        const float dc = i1.z - t1.z, dd = i1.w - t1.w;
        sl += fabsf(0.5f * ( da + db + dc + dd));
        sh += fabsf(0.5f * (-da - db + dc + dd))
            + fabsf(0.5f * (-da + db - dc + dd))
            + fabsf(0.5f * ( da - db - dc + dd));
    }

    // wave-64 butterfly reduce
    #pragma unroll
    for (int off = 32; off > 0; off >>= 1) {
        sl += __shfl_down(sl, off, 64);
        sh += __shfl_down(sh, off, 64);
    }

    __shared__ float red[8];  // 4 waves x {low, high}
    const int lane = threadIdx.x & 63;
    const int wave = threadIdx.x >> 6;
    if (lane == 0) { red[wave] = sl; red[4 + wave] = sh; }
    __syncthreads();
    if (threadIdx.x == 0) {
        // SoA partials: ws[0..NBLK) = low, ws[NBLK..2*NBLK) = high.
        // Plain stores — no atomic contention.
        ws[blockIdx.x]        = red[0] + red[1] + red[2] + red[3];
        ws[NBLK + blockIdx.x] = red[4] + red[5] + red[6] + red[7];
    }
}

__global__ __launch_bounds__(256) void haar_finalize_kernel(
    const float* __restrict__ ws, float* __restrict__ out)
{
    const int tid = threadIdx.x;
    float sl = 0.f, sh = 0.f;
    #pragma unroll
    for (int i = tid; i < NBLK; i += 256) {
        sl += ws[i];
        sh += ws[NBLK + i];
    }
    #pragma unroll
    for (int off = 32; off > 0; off >>= 1) {
        sl += __shfl_down(sl, off, 64);
        sh += __shfl_down(sh, off, 64);
    }
    __shared__ float red[8];
    const int lane = tid & 63;
    const int wave = tid >> 6;
    if (lane == 0) { red[wave] = sl; red[4 + wave] = sh; }
    __syncthreads();
    if (tid == 0) {
        out[0] = (red[0] + red[1] + red[2] + red[3]) / N_LOW;
        out[1] = (red[4] + red[5] + red[6] + red[7]) / (3.0f * N_LOW);
    }
}

extern "C" void kernel_launch(void* const* d_in, const int* in_sizes, int n_in,
                              void* d_out, int out_size, void* d_ws, size_t ws_size,
                              hipStream_t stream) {
    const float* inp = (const float*)d_in[0];
    const float* tgt = (const float*)d_in[1];
    float* out = (float*)d_out;
    float* ws  = (float*)d_ws;

    // ws[0..8192) fully written by haar_loss_kernel — no memset required.
    haar_loss_kernel<<<NBLK, 256, 0, stream>>>(inp, tgt, ws);
    haar_finalize_kernel<<<1, 256, 0, stream>>>(ws, out);
}